// Round 8
// baseline (9022.466 us; speedup 1.0000x reference)
//
#include <hip/hip_runtime.h>
#include <cstdint>
#include <cstddef>

#define L_SEQ 2048
#define H_DIM 1024
#define NBLK  64      // scan blocks per sequence (16 rows each)
#define SCAN_T 512    // threads per block (scan and worker roles)
#define NWORK 128     // gemm worker blocks (idle CUs)
#define TTILE 128     // tokens per gx tile
#define NTILE (L_SEQ / TTILE)   // 16 tiles per sequence
#define AGENT __HIP_MEMORY_SCOPE_AGENT

typedef unsigned long long u64;
typedef __attribute__((ext_vector_type(4))) float f32x4;
typedef __attribute__((ext_vector_type(4))) unsigned int u32x4;

__device__ __forceinline__ float sigmoid_f(float x) {
  return 1.0f / (1.0f + __expf(-x));
}
__device__ __forceinline__ float tanh_f(float x) {
  return 1.0f - 2.0f / (__expf(2.0f * x) + 1.0f);
}

// ---------------------------------------------------------------------------
// init: pack h0 with tag 0 into parity-buffer 0; sentinels into buffer 1;
// zero gx tile-ready counters and per-block h flags.
// ---------------------------------------------------------------------------
__global__ void init_kernel(const float* __restrict__ h01, const float* __restrict__ h02,
                            u64* __restrict__ hb1, u64* __restrict__ hb2,
                            int* __restrict__ done, unsigned* __restrict__ hflags) {
  const int tid = threadIdx.x;  // 256 threads
  if (tid < 2 * NTILE) done[tid] = 0;
  if (tid < 2 * NBLK) hflags[tid] = 0;   // flag[b] = v  <=>  h(v) published
  for (int i = tid; i < H_DIM; i += 256) {
    hb1[i] = (u64)__float_as_uint(h01[i]);          // tag 0 | h0 bits
    hb2[i] = (u64)__float_as_uint(h02[i]);
    hb1[H_DIM + i] = 0x7FFFFFFFull << 32;           // sentinel tag
    hb2[H_DIM + i] = 0x7FFFFFFFull << 32;
  }
}

// ---------------------------------------------------------------------------
// fused cooperative kernel: blocks [0,128) = LSTM scan, [128,256) = gx GEMM
// workers (unchanged from r7).
//
// Scan h-exchange is now FLAG-GATED to kill LLC poll contention (r7: 65536
// threads re-loading 16B tag-words every ~RTT ~= 4-5 TB/s of poll demand ->
// queueing inflated every RTT; ~1.6us/step of comm):
//   producers: lane0 per row stores tag-embedded h word (relaxed, as r7);
//     one lane per block (tid=480, last wave) also stores hflags[b]=t+1.
//   consumers: spin on ONE 4B flag each (flags[tid>>3], wave-coalesced ->
//     ~64x fewer LLC requests), then load the 16B h pair ONCE, tag-verified
//     (catches flag/data reorder and producer wave-skew; no ordering ack
//     needed anywhere).
// Deadlock-free: flag[Q]=t+1 implies Q finished reading step t, so a tag-t+2
// overwrite of parity (t&1) cannot precede any reader of step t.
// ---------------------------------------------------------------------------
__global__ __launch_bounds__(SCAN_T, 2) void fused_kernel(
    const float* __restrict__ W_hh,
    const int* __restrict__ s1, const int* __restrict__ s2,
    const float* __restrict__ emb, const float* __restrict__ W_ih,
    const float* __restrict__ b_ih, const float* __restrict__ b_hh,
    float* __restrict__ gx1, float* __restrict__ gx2,
    const float* __restrict__ c01, const float* __restrict__ c02,
    u64* __restrict__ hb1, u64* __restrict__ hb2,
    int* __restrict__ done, unsigned* __restrict__ hflags) {
  __shared__ float smem[4096];  // 16KB: worker A/B tiles, scan parity buffers
  const int blk = blockIdx.x;
  const int tid = threadIdx.x;

  if (blk >= 2 * NBLK) {
    // ------------------------------ worker path ---------------------------
    const int wid = blk - 2 * NBLK;
    float (*As)[128] = (float(*)[128])smem;          // [16][128]
    float (*Bs)[128] = (float(*)[128])(smem + 2048); // [16][128]
    const int ti = tid >> 5;   // 0..15 : 8 output rows each
    const int tj = tid & 31;   // 0..31 : 4 output cols each
    const int lr = tid >> 2;   // 0..127: tile row this thread stages
    const int k4 = (tid & 3) * 4;

    for (int g = wid; g < 2 * NTILE * 32; g += NWORK) {
      const int tau = g >> 6;
      const int s   = (g >> 5) & 1;
      const int n   = g & 31;
      const int m0  = tau * TTILE;
      const int n0  = n * 128;
      const int* __restrict__ tok = s ? s2 : s1;
      float* __restrict__ gxp = s ? gx2 : gx1;

      const int arow = tok[m0 + lr];
      const float* aptr = emb + (size_t)arow * H_DIM + k4;
      const float* bptr = W_ih + (size_t)(n0 + lr) * H_DIM + k4;

      float acc[8][4];
#pragma unroll
      for (int i = 0; i < 8; ++i)
#pragma unroll
        for (int jj = 0; jj < 4; ++jj) acc[i][jj] = 0.f;

      for (int k0 = 0; k0 < H_DIM; k0 += 16) {
        const float4 av = *(const float4*)(aptr + k0);
        const float4 bv = *(const float4*)(bptr + k0);
        __syncthreads();  // protect previous iteration's LDS reads
        As[k4 + 0][lr] = av.x; As[k4 + 1][lr] = av.y;
        As[k4 + 2][lr] = av.z; As[k4 + 3][lr] = av.w;
        Bs[k4 + 0][lr] = bv.x; Bs[k4 + 1][lr] = bv.y;
        Bs[k4 + 2][lr] = bv.z; Bs[k4 + 3][lr] = bv.w;
        __syncthreads();
#pragma unroll
        for (int k = 0; k < 16; ++k) {
          float a[8], bb[4];
          *(float4*)&a[0] = *(const float4*)&As[k][ti * 8];
          *(float4*)&a[4] = *(const float4*)&As[k][ti * 8 + 4];
          *(float4*)&bb[0] = *(const float4*)&Bs[k][tj * 4];
#pragma unroll
          for (int i = 0; i < 8; ++i)
#pragma unroll
            for (int jj = 0; jj < 4; ++jj)
              acc[i][jj] = fmaf(a[i], bb[jj], acc[i][jj]);
        }
      }

      float bias[4];
#pragma unroll
      for (int jj = 0; jj < 4; ++jj) {
        const int nn = n0 + tj * 4 + jj;
        bias[jj] = b_ih[nn] + b_hh[nn];
      }
#pragma unroll
      for (int i = 0; i < 8; ++i) {
        const int m = m0 + ti * 8 + i;
        unsigned* dst = (unsigned*)(gxp + (size_t)m * (4 * H_DIM) + n0 + tj * 4);
#pragma unroll
        for (int jj = 0; jj < 4; ++jj)
          __hip_atomic_store(dst + jj, __float_as_uint(acc[i][jj] + bias[jj]),
                             __ATOMIC_RELAXED, AGENT);
      }
      __syncthreads();  // drains all threads' stores (vmcnt 0 before barrier)
      if (tid == 0)
        __hip_atomic_fetch_add(&done[s * NTILE + tau], 1, __ATOMIC_RELEASE, AGENT);
    }
    return;
  }

  // -------------------------------- scan path -----------------------------
  const int seq = (blk >= NBLK) ? 1 : 0;
  const int b = blk - seq * NBLK;
  const float* __restrict__ gx = seq ? gx2 : gx1;
  u64* hb = seq ? hb2 : hb1;
  const float* c0 = seq ? c02 : c01;
  int* dct = done + seq * NTILE;
  unsigned* hfl = hflags + seq * NBLK;

  const int g = tid >> 5;       // 0..15 : row within block
  const int u = tid & 31;       // 0..31 : 32-wide k-slice
  const int j = b * 16 + g;     // owned output row

  // per-gate base pointers for this thread's 32-float slice
  const float* wp0 = W_hh + (((size_t)(0 * H_DIM + j)) << 10) + (u << 5);
  const float* wp1 = W_hh + (((size_t)(1 * H_DIM + j)) << 10) + (u << 5);
  const float* wp2 = W_hh + (((size_t)(2 * H_DIM + j)) << 10) + (u << 5);
  const float* wp3 = W_hh + (((size_t)(3 * H_DIM + j)) << 10) + (u << 5);

  // asm-forced weight residency (non-remat-able; allocator keeps in VGPR/AGPR)
  f32x4 W0[8], W1[8], W2[8], W3[8];
#define ALD(dst, base, OFF) \
  asm volatile("global_load_dwordx4 %0, %1, off offset:" OFF \
               : "=v"(dst) : "v"(base))
  ALD(W0[0], wp0, "0");  ALD(W0[1], wp0, "16"); ALD(W0[2], wp0, "32");
  ALD(W0[3], wp0, "48"); ALD(W0[4], wp0, "64"); ALD(W0[5], wp0, "80");
  ALD(W0[6], wp0, "96"); ALD(W0[7], wp0, "112");
  ALD(W1[0], wp1, "0");  ALD(W1[1], wp1, "16"); ALD(W1[2], wp1, "32");
  ALD(W1[3], wp1, "48"); ALD(W1[4], wp1, "64"); ALD(W1[5], wp1, "80");
  ALD(W1[6], wp1, "96"); ALD(W1[7], wp1, "112");
  ALD(W2[0], wp2, "0");  ALD(W2[1], wp2, "16"); ALD(W2[2], wp2, "32");
  ALD(W2[3], wp2, "48"); ALD(W2[4], wp2, "64"); ALD(W2[5], wp2, "80");
  ALD(W2[6], wp2, "96"); ALD(W2[7], wp2, "112");
  ALD(W3[0], wp3, "0");  ALD(W3[1], wp3, "16"); ALD(W3[2], wp3, "32");
  ALD(W3[3], wp3, "48"); ALD(W3[4], wp3, "64"); ALD(W3[5], wp3, "80");
  ALD(W3[6], wp3, "96"); ALD(W3[7], wp3, "112");
#undef ALD
  asm volatile("s_waitcnt vmcnt(0)" ::: "memory");
  __builtin_amdgcn_sched_barrier(0);

  float c = (u == 0) ? c0[j] : 0.0f;

  const int i0 = tid * 2;                        // this thread's 2 h-words
  const int stg = (i0 >> 5) * 33 + (i0 & 31);    // staging offset (floats)
  const unsigned* myfl = hfl + (tid >> 3);       // producer block of my words

  // gate for tile 0, then prefetch gx[0]
  if (tid == 0) {
    while (__hip_atomic_load(&dct[0], __ATOMIC_ACQUIRE, AGENT) < 32) { }
  }
  __syncthreads();

  float gxc0 = 0.f, gxc1 = 0.f, gxc2 = 0.f, gxc3 = 0.f;
  if (u == 0) {
    const unsigned* gp = (const unsigned*)(gx + j);
    gxc0 = __uint_as_float(__hip_atomic_load(gp,            __ATOMIC_RELAXED, AGENT));
    gxc1 = __uint_as_float(__hip_atomic_load(gp + H_DIM,     __ATOMIC_RELAXED, AGENT));
    gxc2 = __uint_as_float(__hip_atomic_load(gp + 2 * H_DIM, __ATOMIC_RELAXED, AGENT));
    gxc3 = __uint_as_float(__hip_atomic_load(gp + 3 * H_DIM, __ATOMIC_RELAXED, AGENT));
  }

  for (int t = 0; t < L_SEQ; ++t) {
    const int tp = (t + 1 < L_SEQ) ? t + 1 : t;
    // gate the tile containing step tp (workers run far ahead)
    if (tp != t && (tp & (TTILE - 1)) == 0) {
      if (tid == 0) {
        while (__hip_atomic_load(&dct[tp >> 7], __ATOMIC_ACQUIRE, AGENT) < 32) { }
      }
      __syncthreads();
    }
    // issue next step's gx loads (hidden under this step's poll + compute)
    float gxn0 = 0.f, gxn1 = 0.f, gxn2 = 0.f, gxn3 = 0.f;
    if (u == 0) {
      const unsigned* gp = (const unsigned*)(gx + (size_t)tp * (4 * H_DIM) + j);
      gxn0 = __uint_as_float(__hip_atomic_load(gp,            __ATOMIC_RELAXED, AGENT));
      gxn1 = __uint_as_float(__hip_atomic_load(gp + H_DIM,     __ATOMIC_RELAXED, AGENT));
      gxn2 = __uint_as_float(__hip_atomic_load(gp + 2 * H_DIM, __ATOMIC_RELAXED, AGENT));
      gxn3 = __uint_as_float(__hip_atomic_load(gp + 3 * H_DIM, __ATOMIC_RELAXED, AGENT));
    }
    // ---- flag-gated exchange: spin on ONE 4B flag (coalesced per wave) ----
    while (__hip_atomic_load(myfl, __ATOMIC_RELAXED, AGENT) < (unsigned)t) { }
    // ---- then load both h-words ONCE; tag-verify (reorder/skew guard) ----
    const u64* src = hb + ((t & 1) << 10) + i0;
    const unsigned tg = (unsigned)t;
    u32x4 pw;
    for (;;) {
      asm volatile("global_load_dwordx4 %0, %1, off sc0 sc1\n\t"
                   "s_waitcnt vmcnt(0)"
                   : "=v"(pw) : "v"(src) : "memory");
      if ((pw[1] == tg) & (pw[3] == tg)) break;
    }
    float* sb = smem + (t & 1) * 1056;
    sb[stg + 0] = __uint_as_float(pw[0]);
    sb[stg + 1] = __uint_as_float(pw[2]);
    __syncthreads();  // the only per-step barrier (parity dbuf covers WAR)
    // 128 FMAs, all literal indices
    const float* hs = sb + u * 33;
    float a0 = 0.f, a1 = 0.f, a2 = 0.f, a3 = 0.f;
#define FMA_GRP(i) do {                                                  \
    const float h0 = hs[4*(i)+0], h1 = hs[4*(i)+1];                      \
    const float h2 = hs[4*(i)+2], h3 = hs[4*(i)+3];                      \
    a0 = fmaf(W0[i][0], h0, a0); a0 = fmaf(W0[i][1], h1, a0);            \
    a0 = fmaf(W0[i][2], h2, a0); a0 = fmaf(W0[i][3], h3, a0);            \
    a1 = fmaf(W1[i][0], h0, a1); a1 = fmaf(W1[i][1], h1, a1);            \
    a1 = fmaf(W1[i][2], h2, a1); a1 = fmaf(W1[i][3], h3, a1);            \
    a2 = fmaf(W2[i][0], h0, a2); a2 = fmaf(W2[i][1], h1, a2);            \
    a2 = fmaf(W2[i][2], h2, a2); a2 = fmaf(W2[i][3], h3, a2);            \
    a3 = fmaf(W3[i][0], h0, a3); a3 = fmaf(W3[i][1], h1, a3);            \
    a3 = fmaf(W3[i][2], h2, a3); a3 = fmaf(W3[i][3], h3, a3); } while (0)
    FMA_GRP(0); FMA_GRP(1); FMA_GRP(2); FMA_GRP(3);
    FMA_GRP(4); FMA_GRP(5); FMA_GRP(6); FMA_GRP(7);
#undef FMA_GRP
    // 32-lane butterfly reduce (lanes u and u+32 hold identical values)
#pragma unroll
    for (int offx = 16; offx >= 1; offx >>= 1) {
      a0 += __shfl_xor(a0, offx, 32);
      a1 += __shfl_xor(a1, offx, 32);
      a2 += __shfl_xor(a2, offx, 32);
      a3 += __shfl_xor(a3, offx, 32);
    }
    if (u == 0) {
      const float gi = a0 + gxc0;
      const float gf = a1 + gxc1;
      const float gg = a2 + gxc2;
      const float go = a3 + gxc3;
      c = sigmoid_f(gf) * c + sigmoid_f(gi) * tanh_f(gg);
      const float hn = sigmoid_f(go) * tanh_f(c);
      const u64 pk = ((u64)(unsigned)(t + 1) << 32) | (u64)__float_as_uint(hn);
      __hip_atomic_store(hb + (((t + 1) & 1) << 10) + j, pk,
                         __ATOMIC_RELAXED, AGENT);
      gxc0 = gxn0; gxc1 = gxn1; gxc2 = gxn2; gxc3 = gxn3;
    }
    // per-block "published" flag: last wave's lane0, right after its h store
    if (tid == SCAN_T - 32) {
      __hip_atomic_store(hfl + b, (unsigned)(t + 1), __ATOMIC_RELAXED, AGENT);
    }
  }
}

// ---------------------------------------------------------------------------
// head: feat = [v1, v2, |v1-v2|, v1*v2]; out = fc2_w @ (fc1_w@feat + fc1_b) + fc2_b
// ---------------------------------------------------------------------------
__global__ __launch_bounds__(512) void head_kernel(
    const u64* __restrict__ h1p, const u64* __restrict__ h2p,
    const float* __restrict__ fc1_w, const float* __restrict__ fc1_b,
    const float* __restrict__ fc2_w, const float* __restrict__ fc2_b,
    float* __restrict__ out) {
  __shared__ float feat[4 * H_DIM];
  __shared__ float yv[512];
  const int tid = threadIdx.x;
  for (int i = tid; i < H_DIM; i += 512) {
    const float a = __uint_as_float((unsigned)h1p[i]);
    const float bsv = __uint_as_float((unsigned)h2p[i]);
    feat[i] = a;
    feat[H_DIM + i] = bsv;
    feat[2 * H_DIM + i] = fabsf(a - bsv);
    feat[3 * H_DIM + i] = a * bsv;
  }
  __syncthreads();
  float s = fc1_b[tid];
  const float4* wr = (const float4*)(fc1_w + (size_t)tid * (4 * H_DIM));
#pragma unroll 4
  for (int k4 = 0; k4 < H_DIM; ++k4) {
    const float4 wv = wr[k4];
    const float4 fv = *(const float4*)&feat[k4 * 4];
    s = fmaf(wv.x, fv.x, s);
    s = fmaf(wv.y, fv.y, s);
    s = fmaf(wv.z, fv.z, s);
    s = fmaf(wv.w, fv.w, s);
  }
  yv[tid] = s;
  __syncthreads();
  if (tid < 64) {
    float s0 = 0.f, s1 = 0.f;
    for (int i = tid; i < 512; i += 64) {
      s0 = fmaf(fc2_w[i], yv[i], s0);
      s1 = fmaf(fc2_w[512 + i], yv[i], s1);
    }
#pragma unroll
    for (int off = 32; off >= 1; off >>= 1) {
      s0 += __shfl_down(s0, off);
      s1 += __shfl_down(s1, off);
    }
    if (tid == 0) {
      out[0] = s0 + fc2_b[0];
      out[1] = s1 + fc2_b[1];
    }
  }
}

// ---------------------------------------------------------------------------
extern "C" void kernel_launch(void* const* d_in, const int* in_sizes, int n_in,
                              void* d_out, int out_size, void* d_ws, size_t ws_size,
                              hipStream_t stream) {
  const int*   s1    = (const int*)  d_in[0];
  const int*   s2    = (const int*)  d_in[1];
  const float* emb   = (const float*)d_in[2];
  const float* W_ih  = (const float*)d_in[3];
  const float* W_hh  = (const float*)d_in[4];
  const float* b_ih  = (const float*)d_in[5];
  const float* b_hh  = (const float*)d_in[6];
  const float* h01   = (const float*)d_in[7];
  const float* c01   = (const float*)d_in[8];
  const float* h02   = (const float*)d_in[9];
  const float* c02   = (const float*)d_in[10];
  const float* fc1_w = (const float*)d_in[11];
  const float* fc1_b = (const float*)d_in[12];
  const float* fc2_w = (const float*)d_in[13];
  const float* fc2_b = (const float*)d_in[14];
  float* out = (float*)d_out;

  // workspace layout
  const size_t GX = (size_t)L_SEQ * 4 * H_DIM;  // 8M floats per sequence
  float* ws = (float*)d_ws;
  float* gx1 = ws;
  float* gx2 = ws + GX;
  u64* hb1 = (u64*)(ws + 2 * GX);      // [2][1024] packed (tag|h) double buffer
  u64* hb2 = hb1 + 2 * H_DIM;
  int* done = (int*)(hb2 + 2 * H_DIM); // 32 tile-ready counters
  unsigned* hflags = (unsigned*)(done + 32);  // 128 per-block h flags

  init_kernel<<<1, 256, 0, stream>>>(h01, h02, hb1, hb2, done, hflags);

  void* args[] = { (void*)&W_hh, (void*)&s1, (void*)&s2, (void*)&emb,
                   (void*)&W_ih, (void*)&b_ih, (void*)&b_hh,
                   (void*)&gx1, (void*)&gx2, (void*)&c01, (void*)&c02,
                   (void*)&hb1, (void*)&hb2, (void*)&done, (void*)&hflags };
  hipLaunchCooperativeKernel(reinterpret_cast<void*>(fused_kernel),
                             dim3(2 * NBLK + NWORK), dim3(SCAN_T), args, 0, stream);

  head_kernel<<<1, 512, 0, stream>>>(hb1, hb2, fc1_w, fc1_b, fc2_w, fc2_b, out);
}

// Round 11
// 4362.554 us; speedup vs baseline: 2.0682x; 2.0682x over previous
//
#include <hip/hip_runtime.h>
#include <cstdint>
#include <cstddef>

#define L_SEQ 2048
#define H_DIM 1024
#define NBLK  64      // scan blocks per sequence (16 rows each)
#define SCAN_T 512    // threads per block (scan and worker roles)
#define NWORK 128     // gemm worker blocks (idle CUs)
#define TTILE 128     // tokens per gx tile
#define NTILE (L_SEQ / TTILE)   // 16 tiles per sequence
#define AGENT __HIP_MEMORY_SCOPE_AGENT

typedef unsigned long long u64;
typedef __attribute__((ext_vector_type(4))) float f32x4;
typedef __attribute__((ext_vector_type(4))) unsigned int u32x4;

__device__ __forceinline__ float sigmoid_f(float x) {
  return 1.0f / (1.0f + __expf(-x));
}
__device__ __forceinline__ float tanh_f(float x) {
  return 1.0f - 2.0f / (__expf(2.0f * x) + 1.0f);
}

// ---------------------------------------------------------------------------
// init: pack h0 with tag 0 into parity-buffer 0; sentinels into buffer 1;
// zero gx tile-ready counters.
// ---------------------------------------------------------------------------
__global__ void init_kernel(const float* __restrict__ h01, const float* __restrict__ h02,
                            u64* __restrict__ hb1, u64* __restrict__ hb2,
                            int* __restrict__ done) {
  const int tid = threadIdx.x;  // 256 threads
  if (tid < 2 * NTILE) done[tid] = 0;
  for (int i = tid; i < H_DIM; i += 256) {
    hb1[i] = (u64)__float_as_uint(h01[i]);          // tag 0 | h0 bits
    hb2[i] = (u64)__float_as_uint(h02[i]);
    hb1[H_DIM + i] = 0x7FFFFFFFull << 32;           // sentinel tag
    hb2[H_DIM + i] = 0x7FFFFFFFull << 32;
  }
}

// ---------------------------------------------------------------------------
// fused cooperative kernel: blocks [0,128) = LSTM scan, [128,256) = gx GEMM
// workers. EXACT r7 structure (proven 2.05us/step, absmax 0.0) with ONE
// change: h publish via atomic EXCHANGE instead of atomic store.
//
// Rationale: r7's step = 0.4us compute + ~1.65us comm. With LLC load RTT
// ~375-500ns (m126), the comm decomposes as V (publish->visibility) +
// ~1.5*RTT -> V ~= 1us: the STORE-visibility leg dominates. An atomic
// exchange executes at the coherence point (LLC), so the new value should
// become visible in ~RTT/2 instead of the write-through path's ~1us.
// Semantics unchanged: same 8B atomicity, relaxed/agent, old value dropped.
//
// r9/r10's pipelined staggered polling is ABANDONED: in-flight asm loads
// targeting registers across compiler-generated code cannot be made safe at
// HIP level (live-range splits move the value to a different physical quad;
// the retirement then clobbers unrelated values). Two absmax failures
// confirmed. Poll is r7's single dwordx4 + vmcnt(0), tag-self-validated.
// ---------------------------------------------------------------------------
__global__ __launch_bounds__(SCAN_T, 2) void fused_kernel(
    const float* __restrict__ W_hh,
    const int* __restrict__ s1, const int* __restrict__ s2,
    const float* __restrict__ emb, const float* __restrict__ W_ih,
    const float* __restrict__ b_ih, const float* __restrict__ b_hh,
    float* __restrict__ gx1, float* __restrict__ gx2,
    const float* __restrict__ c01, const float* __restrict__ c02,
    u64* __restrict__ hb1, u64* __restrict__ hb2,
    int* __restrict__ done) {
  __shared__ float smem[4096];  // 16KB: worker A/B tiles, scan parity buffers
  const int blk = blockIdx.x;
  const int tid = threadIdx.x;

  if (blk >= 2 * NBLK) {
    // ------------------------------ worker path ---------------------------
    const int wid = blk - 2 * NBLK;
    float (*As)[128] = (float(*)[128])smem;          // [16][128]
    float (*Bs)[128] = (float(*)[128])(smem + 2048); // [16][128]
    const int ti = tid >> 5;   // 0..15 : 8 output rows each
    const int tj = tid & 31;   // 0..31 : 4 output cols each
    const int lr = tid >> 2;   // 0..127: tile row this thread stages
    const int k4 = (tid & 3) * 4;

    for (int g = wid; g < 2 * NTILE * 32; g += NWORK) {
      const int tau = g >> 6;
      const int s   = (g >> 5) & 1;
      const int n   = g & 31;
      const int m0  = tau * TTILE;
      const int n0  = n * 128;
      const int* __restrict__ tok = s ? s2 : s1;
      float* __restrict__ gxp = s ? gx2 : gx1;

      const int arow = tok[m0 + lr];
      const float* aptr = emb + (size_t)arow * H_DIM + k4;
      const float* bptr = W_ih + (size_t)(n0 + lr) * H_DIM + k4;

      float acc[8][4];
#pragma unroll
      for (int i = 0; i < 8; ++i)
#pragma unroll
        for (int jj = 0; jj < 4; ++jj) acc[i][jj] = 0.f;

      for (int k0 = 0; k0 < H_DIM; k0 += 16) {
        const float4 av = *(const float4*)(aptr + k0);
        const float4 bv = *(const float4*)(bptr + k0);
        __syncthreads();  // protect previous iteration's LDS reads
        As[k4 + 0][lr] = av.x; As[k4 + 1][lr] = av.y;
        As[k4 + 2][lr] = av.z; As[k4 + 3][lr] = av.w;
        Bs[k4 + 0][lr] = bv.x; Bs[k4 + 1][lr] = bv.y;
        Bs[k4 + 2][lr] = bv.z; Bs[k4 + 3][lr] = bv.w;
        __syncthreads();
#pragma unroll
        for (int k = 0; k < 16; ++k) {
          float a[8], bb[4];
          *(float4*)&a[0] = *(const float4*)&As[k][ti * 8];
          *(float4*)&a[4] = *(const float4*)&As[k][ti * 8 + 4];
          *(float4*)&bb[0] = *(const float4*)&Bs[k][tj * 4];
#pragma unroll
          for (int i = 0; i < 8; ++i)
#pragma unroll
            for (int jj = 0; jj < 4; ++jj)
              acc[i][jj] = fmaf(a[i], bb[jj], acc[i][jj]);
        }
      }

      float bias[4];
#pragma unroll
      for (int jj = 0; jj < 4; ++jj) {
        const int nn = n0 + tj * 4 + jj;
        bias[jj] = b_ih[nn] + b_hh[nn];
      }
#pragma unroll
      for (int i = 0; i < 8; ++i) {
        const int m = m0 + ti * 8 + i;
        unsigned* dst = (unsigned*)(gxp + (size_t)m * (4 * H_DIM) + n0 + tj * 4);
#pragma unroll
        for (int jj = 0; jj < 4; ++jj)
          __hip_atomic_store(dst + jj, __float_as_uint(acc[i][jj] + bias[jj]),
                             __ATOMIC_RELAXED, AGENT);
      }
      __syncthreads();  // drains all threads' stores (vmcnt 0 before barrier)
      if (tid == 0)
        __hip_atomic_fetch_add(&done[s * NTILE + tau], 1, __ATOMIC_RELEASE, AGENT);
    }
    return;
  }

  // -------------------------------- scan path -----------------------------
  const int seq = (blk >= NBLK) ? 1 : 0;
  const int b = blk - seq * NBLK;
  const float* __restrict__ gx = seq ? gx2 : gx1;
  u64* hb = seq ? hb2 : hb1;
  const float* c0 = seq ? c02 : c01;
  int* dct = done + seq * NTILE;

  const int g = tid >> 5;       // 0..15 : row within block
  const int u = tid & 31;       // 0..31 : 32-wide k-slice
  const int j = b * 16 + g;     // owned output row

  // per-gate base pointers for this thread's 32-float slice
  const float* wp0 = W_hh + (((size_t)(0 * H_DIM + j)) << 10) + (u << 5);
  const float* wp1 = W_hh + (((size_t)(1 * H_DIM + j)) << 10) + (u << 5);
  const float* wp2 = W_hh + (((size_t)(2 * H_DIM + j)) << 10) + (u << 5);
  const float* wp3 = W_hh + (((size_t)(3 * H_DIM + j)) << 10) + (u << 5);

  // asm-forced weight residency (non-remat-able; allocator keeps in VGPR/AGPR)
  f32x4 W0[8], W1[8], W2[8], W3[8];
#define ALD(dst, base, OFF) \
  asm volatile("global_load_dwordx4 %0, %1, off offset:" OFF \
               : "=v"(dst) : "v"(base))
  ALD(W0[0], wp0, "0");  ALD(W0[1], wp0, "16"); ALD(W0[2], wp0, "32");
  ALD(W0[3], wp0, "48"); ALD(W0[4], wp0, "64"); ALD(W0[5], wp0, "80");
  ALD(W0[6], wp0, "96"); ALD(W0[7], wp0, "112");
  ALD(W1[0], wp1, "0");  ALD(W1[1], wp1, "16"); ALD(W1[2], wp1, "32");
  ALD(W1[3], wp1, "48"); ALD(W1[4], wp1, "64"); ALD(W1[5], wp1, "80");
  ALD(W1[6], wp1, "96"); ALD(W1[7], wp1, "112");
  ALD(W2[0], wp2, "0");  ALD(W2[1], wp2, "16"); ALD(W2[2], wp2, "32");
  ALD(W2[3], wp2, "48"); ALD(W2[4], wp2, "64"); ALD(W2[5], wp2, "80");
  ALD(W2[6], wp2, "96"); ALD(W2[7], wp2, "112");
  ALD(W3[0], wp3, "0");  ALD(W3[1], wp3, "16"); ALD(W3[2], wp3, "32");
  ALD(W3[3], wp3, "48"); ALD(W3[4], wp3, "64"); ALD(W3[5], wp3, "80");
  ALD(W3[6], wp3, "96"); ALD(W3[7], wp3, "112");
#undef ALD
  asm volatile("s_waitcnt vmcnt(0)" ::: "memory");
  __builtin_amdgcn_sched_barrier(0);

  float c = (u == 0) ? c0[j] : 0.0f;

  const int i0 = tid * 2;                        // this thread's 2 h-words
  const int stg = (i0 >> 5) * 33 + (i0 & 31);    // staging offset (floats)

  // gate for tile 0, then prefetch gx[0]
  if (tid == 0) {
    while (__hip_atomic_load(&dct[0], __ATOMIC_ACQUIRE, AGENT) < 32) { }
  }
  __syncthreads();

  float gxc0 = 0.f, gxc1 = 0.f, gxc2 = 0.f, gxc3 = 0.f;
  if (u == 0) {
    const unsigned* gp = (const unsigned*)(gx + j);
    gxc0 = __uint_as_float(__hip_atomic_load(gp,            __ATOMIC_RELAXED, AGENT));
    gxc1 = __uint_as_float(__hip_atomic_load(gp + H_DIM,     __ATOMIC_RELAXED, AGENT));
    gxc2 = __uint_as_float(__hip_atomic_load(gp + 2 * H_DIM, __ATOMIC_RELAXED, AGENT));
    gxc3 = __uint_as_float(__hip_atomic_load(gp + 3 * H_DIM, __ATOMIC_RELAXED, AGENT));
  }

  for (int t = 0; t < L_SEQ; ++t) {
    const int tp = (t + 1 < L_SEQ) ? t + 1 : t;
    // gate the tile containing step tp (workers run far ahead)
    if (tp != t && (tp & (TTILE - 1)) == 0) {
      if (tid == 0) {
        while (__hip_atomic_load(&dct[tp >> 7], __ATOMIC_ACQUIRE, AGENT) < 32) { }
      }
      __syncthreads();
    }
    // issue next step's gx loads (hidden under this step's poll + compute)
    float gxn0 = 0.f, gxn1 = 0.f, gxn2 = 0.f, gxn3 = 0.f;
    if (u == 0) {
      const unsigned* gp = (const unsigned*)(gx + (size_t)tp * (4 * H_DIM) + j);
      gxn0 = __uint_as_float(__hip_atomic_load(gp,            __ATOMIC_RELAXED, AGENT));
      gxn1 = __uint_as_float(__hip_atomic_load(gp + H_DIM,     __ATOMIC_RELAXED, AGENT));
      gxn2 = __uint_as_float(__hip_atomic_load(gp + 2 * H_DIM, __ATOMIC_RELAXED, AGENT));
      gxn3 = __uint_as_float(__hip_atomic_load(gp + 3 * H_DIM, __ATOMIC_RELAXED, AGENT));
    }
    // poll both h-words with ONE dwordx4 (sc0 sc1 = LLC-coherent); each 8B
    // half carries its own tag, so 16B tearing is harmless
    const u64* src = hb + ((t & 1) << 10) + i0;
    const unsigned tg = (unsigned)t;
    u32x4 pw;
    for (;;) {
      asm volatile("global_load_dwordx4 %0, %1, off sc0 sc1\n\t"
                   "s_waitcnt vmcnt(0)"
                   : "=v"(pw) : "v"(src) : "memory");
      if ((pw[1] == tg) & (pw[3] == tg)) break;
    }
    float* sb = smem + (t & 1) * 1056;
    sb[stg + 0] = __uint_as_float(pw[0]);
    sb[stg + 1] = __uint_as_float(pw[2]);
    __syncthreads();  // the only per-step barrier (parity dbuf covers WAR)
    // 128 FMAs, all literal indices
    const float* hs = sb + u * 33;
    float a0 = 0.f, a1 = 0.f, a2 = 0.f, a3 = 0.f;
#define FMA_GRP(i) do {                                                  \
    const float h0 = hs[4*(i)+0], h1 = hs[4*(i)+1];                      \
    const float h2 = hs[4*(i)+2], h3 = hs[4*(i)+3];                      \
    a0 = fmaf(W0[i][0], h0, a0); a0 = fmaf(W0[i][1], h1, a0);            \
    a0 = fmaf(W0[i][2], h2, a0); a0 = fmaf(W0[i][3], h3, a0);            \
    a1 = fmaf(W1[i][0], h0, a1); a1 = fmaf(W1[i][1], h1, a1);            \
    a1 = fmaf(W1[i][2], h2, a1); a1 = fmaf(W1[i][3], h3, a1);            \
    a2 = fmaf(W2[i][0], h0, a2); a2 = fmaf(W2[i][1], h1, a2);            \
    a2 = fmaf(W2[i][2], h2, a2); a2 = fmaf(W2[i][3], h3, a2);            \
    a3 = fmaf(W3[i][0], h0, a3); a3 = fmaf(W3[i][1], h1, a3);            \
    a3 = fmaf(W3[i][2], h2, a3); a3 = fmaf(W3[i][3], h3, a3); } while (0)
    FMA_GRP(0); FMA_GRP(1); FMA_GRP(2); FMA_GRP(3);
    FMA_GRP(4); FMA_GRP(5); FMA_GRP(6); FMA_GRP(7);
#undef FMA_GRP
    // 32-lane butterfly reduce (lanes u and u+32 hold identical values)
#pragma unroll
    for (int offx = 16; offx >= 1; offx >>= 1) {
      a0 += __shfl_xor(a0, offx, 32);
      a1 += __shfl_xor(a1, offx, 32);
      a2 += __shfl_xor(a2, offx, 32);
      a3 += __shfl_xor(a3, offx, 32);
    }
    if (u == 0) {
      const float gi = a0 + gxc0;
      const float gf = a1 + gxc1;
      const float gg = a2 + gxc2;
      const float go = a3 + gxc3;
      c = sigmoid_f(gf) * c + sigmoid_f(gi) * tanh_f(gg);
      const float hn = sigmoid_f(go) * tanh_f(c);
      const u64 pk = ((u64)(unsigned)(t + 1) << 32) | (u64)__float_as_uint(hn);
      // publish via atomic EXCHANGE: executes at the LLC (coherence point),
      // cutting the store-visibility leg vs the write-through store path.
      (void)__hip_atomic_exchange(hb + (((t + 1) & 1) << 10) + j, pk,
                                  __ATOMIC_RELAXED, AGENT);
      gxc0 = gxn0; gxc1 = gxn1; gxc2 = gxn2; gxc3 = gxn3;
    }
  }
}

// ---------------------------------------------------------------------------
// head: feat = [v1, v2, |v1-v2|, v1*v2]; out = fc2_w @ (fc1_w@feat + fc1_b) + fc2_b
// ---------------------------------------------------------------------------
__global__ __launch_bounds__(512) void head_kernel(
    const u64* __restrict__ h1p, const u64* __restrict__ h2p,
    const float* __restrict__ fc1_w, const float* __restrict__ fc1_b,
    const float* __restrict__ fc2_w, const float* __restrict__ fc2_b,
    float* __restrict__ out) {
  __shared__ float feat[4 * H_DIM];
  __shared__ float yv[512];
  const int tid = threadIdx.x;
  for (int i = tid; i < H_DIM; i += 512) {
    const float a = __uint_as_float((unsigned)h1p[i]);
    const float bsv = __uint_as_float((unsigned)h2p[i]);
    feat[i] = a;
    feat[H_DIM + i] = bsv;
    feat[2 * H_DIM + i] = fabsf(a - bsv);
    feat[3 * H_DIM + i] = a * bsv;
  }
  __syncthreads();
  float s = fc1_b[tid];
  const float4* wr = (const float4*)(fc1_w + (size_t)tid * (4 * H_DIM));
#pragma unroll 4
  for (int k4 = 0; k4 < H_DIM; ++k4) {
    const float4 wv = wr[k4];
    const float4 fv = *(const float4*)&feat[k4 * 4];
    s = fmaf(wv.x, fv.x, s);
    s = fmaf(wv.y, fv.y, s);
    s = fmaf(wv.z, fv.z, s);
    s = fmaf(wv.w, fv.w, s);
  }
  yv[tid] = s;
  __syncthreads();
  if (tid < 64) {
    float s0 = 0.f, s1 = 0.f;
    for (int i = tid; i < 512; i += 64) {
      s0 = fmaf(fc2_w[i], yv[i], s0);
      s1 = fmaf(fc2_w[512 + i], yv[i], s1);
    }
#pragma unroll
    for (int off = 32; off >= 1; off >>= 1) {
      s0 += __shfl_down(s0, off);
      s1 += __shfl_down(s1, off);
    }
    if (tid == 0) {
      out[0] = s0 + fc2_b[0];
      out[1] = s1 + fc2_b[1];
    }
  }
}

// ---------------------------------------------------------------------------
extern "C" void kernel_launch(void* const* d_in, const int* in_sizes, int n_in,
                              void* d_out, int out_size, void* d_ws, size_t ws_size,
                              hipStream_t stream) {
  const int*   s1    = (const int*)  d_in[0];
  const int*   s2    = (const int*)  d_in[1];
  const float* emb   = (const float*)d_in[2];
  const float* W_ih  = (const float*)d_in[3];
  const float* W_hh  = (const float*)d_in[4];
  const float* b_ih  = (const float*)d_in[5];
  const float* b_hh  = (const float*)d_in[6];
  const float* h01   = (const float*)d_in[7];
  const float* c01   = (const float*)d_in[8];
  const float* h02   = (const float*)d_in[9];
  const float* c02   = (const float*)d_in[10];
  const float* fc1_w = (const float*)d_in[11];
  const float* fc1_b = (const float*)d_in[12];
  const float* fc2_w = (const float*)d_in[13];
  const float* fc2_b = (const float*)d_in[14];
  float* out = (float*)d_out;

  // workspace layout
  const size_t GX = (size_t)L_SEQ * 4 * H_DIM;  // 8M floats per sequence
  float* ws = (float*)d_ws;
  float* gx1 = ws;
  float* gx2 = ws + GX;
  u64* hb1 = (u64*)(ws + 2 * GX);      // [2][1024] packed (tag|h) double buffer
  u64* hb2 = hb1 + 2 * H_DIM;
  int* done = (int*)(hb2 + 2 * H_DIM); // 32 tile-ready counters

  init_kernel<<<1, 256, 0, stream>>>(h01, h02, hb1, hb2, done);

  void* args[] = { (void*)&W_hh, (void*)&s1, (void*)&s2, (void*)&emb,
                   (void*)&W_ih, (void*)&b_ih, (void*)&b_hh,
                   (void*)&gx1, (void*)&gx2, (void*)&c01, (void*)&c02,
                   (void*)&hb1, (void*)&hb2, (void*)&done };
  hipLaunchCooperativeKernel(reinterpret_cast<void*>(fused_kernel),
                             dim3(2 * NBLK + NWORK), dim3(SCAN_T), args, 0, stream);

  head_kernel<<<1, 512, 0, stream>>>(hb1, hb2, fc1_w, fc1_b, fc2_w, fc2_b, out);
}

// Round 13
// 4351.432 us; speedup vs baseline: 2.0734x; 1.0026x over previous
//
#include <hip/hip_runtime.h>
#include <cstdint>
#include <cstddef>

#define L_SEQ 2048
#define H_DIM 1024
#define NBLK  64      // scan blocks per sequence (16 rows each)
#define SCAN_T 512    // threads per block (scan and worker roles)
#define NWORK 128     // gemm worker blocks (idle CUs)
#define TTILE 128     // tokens per gx tile
#define NTILE (L_SEQ / TTILE)   // 16 tiles per sequence
#define AGENT __HIP_MEMORY_SCOPE_AGENT

typedef unsigned long long u64;
typedef __attribute__((ext_vector_type(4))) float f32x4;
typedef __attribute__((ext_vector_type(4))) unsigned int u32x4;

__device__ __forceinline__ float sigmoid_f(float x) {
  return 1.0f / (1.0f + __expf(-x));
}
__device__ __forceinline__ float tanh_f(float x) {
  return 1.0f - 2.0f / (__expf(2.0f * x) + 1.0f);
}

// ---------------------------------------------------------------------------
// init: pack h0 with tag 0 into parity-buffer 0; sentinels into buffer 1;
// zero gx tile-ready counters.
// ---------------------------------------------------------------------------
__global__ void init_kernel(const float* __restrict__ h01, const float* __restrict__ h02,
                            u64* __restrict__ hb1, u64* __restrict__ hb2,
                            int* __restrict__ done) {
  const int tid = threadIdx.x;  // 256 threads
  if (tid < 2 * NTILE) done[tid] = 0;
  for (int i = tid; i < H_DIM; i += 256) {
    hb1[i] = (u64)__float_as_uint(h01[i]);          // tag 0 | h0 bits
    hb2[i] = (u64)__float_as_uint(h02[i]);
    hb1[H_DIM + i] = 0x7FFFFFFFull << 32;           // sentinel tag
    hb2[H_DIM + i] = 0x7FFFFFFFull << 32;
  }
}

// ---------------------------------------------------------------------------
// fused cooperative kernel: blocks [0,128) = LSTM scan, [128,256) = gx GEMM
// workers. This is the r11 kernel verbatim (proven: absmax 0.0, scan
// 2.05us/step) — reverted after r12's XCD-local protocol failed correctness
// (3rd failed sub-LLC attempt: r9 reg-clobber, r10 reg-clobber, r12
// coherence hole). The agent-scope tag-embedded exchange below is the only
// protocol that has ever validated; its ~1.6us/step comm leg is invariant
// under publish mechanism (r11), poll fan-in (r8), and sampling rate (r9).
// ---------------------------------------------------------------------------
__global__ __launch_bounds__(SCAN_T, 2) void fused_kernel(
    const float* __restrict__ W_hh,
    const int* __restrict__ s1, const int* __restrict__ s2,
    const float* __restrict__ emb, const float* __restrict__ W_ih,
    const float* __restrict__ b_ih, const float* __restrict__ b_hh,
    float* __restrict__ gx1, float* __restrict__ gx2,
    const float* __restrict__ c01, const float* __restrict__ c02,
    u64* __restrict__ hb1, u64* __restrict__ hb2,
    int* __restrict__ done) {
  __shared__ float smem[4096];  // 16KB: worker A/B tiles, scan parity buffers
  const int blk = blockIdx.x;
  const int tid = threadIdx.x;

  if (blk >= 2 * NBLK) {
    // ------------------------------ worker path ---------------------------
    const int wid = blk - 2 * NBLK;
    float (*As)[128] = (float(*)[128])smem;          // [16][128]
    float (*Bs)[128] = (float(*)[128])(smem + 2048); // [16][128]
    const int ti = tid >> 5;   // 0..15 : 8 output rows each
    const int tj = tid & 31;   // 0..31 : 4 output cols each
    const int lr = tid >> 2;   // 0..127: tile row this thread stages
    const int k4 = (tid & 3) * 4;

    for (int g = wid; g < 2 * NTILE * 32; g += NWORK) {
      const int tau = g >> 6;
      const int s   = (g >> 5) & 1;
      const int n   = g & 31;
      const int m0  = tau * TTILE;
      const int n0  = n * 128;
      const int* __restrict__ tok = s ? s2 : s1;
      float* __restrict__ gxp = s ? gx2 : gx1;

      const int arow = tok[m0 + lr];
      const float* aptr = emb + (size_t)arow * H_DIM + k4;
      const float* bptr = W_ih + (size_t)(n0 + lr) * H_DIM + k4;

      float acc[8][4];
#pragma unroll
      for (int i = 0; i < 8; ++i)
#pragma unroll
        for (int jj = 0; jj < 4; ++jj) acc[i][jj] = 0.f;

      for (int k0 = 0; k0 < H_DIM; k0 += 16) {
        const float4 av = *(const float4*)(aptr + k0);
        const float4 bv = *(const float4*)(bptr + k0);
        __syncthreads();  // protect previous iteration's LDS reads
        As[k4 + 0][lr] = av.x; As[k4 + 1][lr] = av.y;
        As[k4 + 2][lr] = av.z; As[k4 + 3][lr] = av.w;
        Bs[k4 + 0][lr] = bv.x; Bs[k4 + 1][lr] = bv.y;
        Bs[k4 + 2][lr] = bv.z; Bs[k4 + 3][lr] = bv.w;
        __syncthreads();
#pragma unroll
        for (int k = 0; k < 16; ++k) {
          float a[8], bb[4];
          *(float4*)&a[0] = *(const float4*)&As[k][ti * 8];
          *(float4*)&a[4] = *(const float4*)&As[k][ti * 8 + 4];
          *(float4*)&bb[0] = *(const float4*)&Bs[k][tj * 4];
#pragma unroll
          for (int i = 0; i < 8; ++i)
#pragma unroll
            for (int jj = 0; jj < 4; ++jj)
              acc[i][jj] = fmaf(a[i], bb[jj], acc[i][jj]);
        }
      }

      float bias[4];
#pragma unroll
      for (int jj = 0; jj < 4; ++jj) {
        const int nn = n0 + tj * 4 + jj;
        bias[jj] = b_ih[nn] + b_hh[nn];
      }
#pragma unroll
      for (int i = 0; i < 8; ++i) {
        const int m = m0 + ti * 8 + i;
        unsigned* dst = (unsigned*)(gxp + (size_t)m * (4 * H_DIM) + n0 + tj * 4);
#pragma unroll
        for (int jj = 0; jj < 4; ++jj)
          __hip_atomic_store(dst + jj, __float_as_uint(acc[i][jj] + bias[jj]),
                             __ATOMIC_RELAXED, AGENT);
      }
      __syncthreads();  // drains all threads' stores (vmcnt 0 before barrier)
      if (tid == 0)
        __hip_atomic_fetch_add(&done[s * NTILE + tau], 1, __ATOMIC_RELEASE, AGENT);
    }
    return;
  }

  // -------------------------------- scan path -----------------------------
  const int seq = (blk >= NBLK) ? 1 : 0;
  const int b = blk - seq * NBLK;
  const float* __restrict__ gx = seq ? gx2 : gx1;
  u64* hb = seq ? hb2 : hb1;
  const float* c0 = seq ? c02 : c01;
  int* dct = done + seq * NTILE;

  const int g = tid >> 5;       // 0..15 : row within block
  const int u = tid & 31;       // 0..31 : 32-wide k-slice
  const int j = b * 16 + g;     // owned output row

  // per-gate base pointers for this thread's 32-float slice
  const float* wp0 = W_hh + (((size_t)(0 * H_DIM + j)) << 10) + (u << 5);
  const float* wp1 = W_hh + (((size_t)(1 * H_DIM + j)) << 10) + (u << 5);
  const float* wp2 = W_hh + (((size_t)(2 * H_DIM + j)) << 10) + (u << 5);
  const float* wp3 = W_hh + (((size_t)(3 * H_DIM + j)) << 10) + (u << 5);

  // asm-forced weight residency (non-remat-able; allocator keeps in VGPR/AGPR)
  f32x4 W0[8], W1[8], W2[8], W3[8];
#define ALD(dst, base, OFF) \
  asm volatile("global_load_dwordx4 %0, %1, off offset:" OFF \
               : "=v"(dst) : "v"(base))
  ALD(W0[0], wp0, "0");  ALD(W0[1], wp0, "16"); ALD(W0[2], wp0, "32");
  ALD(W0[3], wp0, "48"); ALD(W0[4], wp0, "64"); ALD(W0[5], wp0, "80");
  ALD(W0[6], wp0, "96"); ALD(W0[7], wp0, "112");
  ALD(W1[0], wp1, "0");  ALD(W1[1], wp1, "16"); ALD(W1[2], wp1, "32");
  ALD(W1[3], wp1, "48"); ALD(W1[4], wp1, "64"); ALD(W1[5], wp1, "80");
  ALD(W1[6], wp1, "96"); ALD(W1[7], wp1, "112");
  ALD(W2[0], wp2, "0");  ALD(W2[1], wp2, "16"); ALD(W2[2], wp2, "32");
  ALD(W2[3], wp2, "48"); ALD(W2[4], wp2, "64"); ALD(W2[5], wp2, "80");
  ALD(W2[6], wp2, "96"); ALD(W2[7], wp2, "112");
  ALD(W3[0], wp3, "0");  ALD(W3[1], wp3, "16"); ALD(W3[2], wp3, "32");
  ALD(W3[3], wp3, "48"); ALD(W3[4], wp3, "64"); ALD(W3[5], wp3, "80");
  ALD(W3[6], wp3, "96"); ALD(W3[7], wp3, "112");
#undef ALD
  asm volatile("s_waitcnt vmcnt(0)" ::: "memory");
  __builtin_amdgcn_sched_barrier(0);

  float c = (u == 0) ? c0[j] : 0.0f;

  const int i0 = tid * 2;                        // this thread's 2 h-words
  const int stg = (i0 >> 5) * 33 + (i0 & 31);    // staging offset (floats)

  // gate for tile 0, then prefetch gx[0]
  if (tid == 0) {
    while (__hip_atomic_load(&dct[0], __ATOMIC_ACQUIRE, AGENT) < 32) { }
  }
  __syncthreads();

  float gxc0 = 0.f, gxc1 = 0.f, gxc2 = 0.f, gxc3 = 0.f;
  if (u == 0) {
    const unsigned* gp = (const unsigned*)(gx + j);
    gxc0 = __uint_as_float(__hip_atomic_load(gp,            __ATOMIC_RELAXED, AGENT));
    gxc1 = __uint_as_float(__hip_atomic_load(gp + H_DIM,     __ATOMIC_RELAXED, AGENT));
    gxc2 = __uint_as_float(__hip_atomic_load(gp + 2 * H_DIM, __ATOMIC_RELAXED, AGENT));
    gxc3 = __uint_as_float(__hip_atomic_load(gp + 3 * H_DIM, __ATOMIC_RELAXED, AGENT));
  }

  for (int t = 0; t < L_SEQ; ++t) {
    const int tp = (t + 1 < L_SEQ) ? t + 1 : t;
    // gate the tile containing step tp (workers run far ahead)
    if (tp != t && (tp & (TTILE - 1)) == 0) {
      if (tid == 0) {
        while (__hip_atomic_load(&dct[tp >> 7], __ATOMIC_ACQUIRE, AGENT) < 32) { }
      }
      __syncthreads();
    }
    // issue next step's gx loads (hidden under this step's poll + compute)
    float gxn0 = 0.f, gxn1 = 0.f, gxn2 = 0.f, gxn3 = 0.f;
    if (u == 0) {
      const unsigned* gp = (const unsigned*)(gx + (size_t)tp * (4 * H_DIM) + j);
      gxn0 = __uint_as_float(__hip_atomic_load(gp,            __ATOMIC_RELAXED, AGENT));
      gxn1 = __uint_as_float(__hip_atomic_load(gp + H_DIM,     __ATOMIC_RELAXED, AGENT));
      gxn2 = __uint_as_float(__hip_atomic_load(gp + 2 * H_DIM, __ATOMIC_RELAXED, AGENT));
      gxn3 = __uint_as_float(__hip_atomic_load(gp + 3 * H_DIM, __ATOMIC_RELAXED, AGENT));
    }
    // poll both h-words with ONE dwordx4 (sc0 sc1 = LLC-coherent); each 8B
    // half carries its own tag, so 16B tearing is harmless
    const u64* src = hb + ((t & 1) << 10) + i0;
    const unsigned tg = (unsigned)t;
    u32x4 pw;
    for (;;) {
      asm volatile("global_load_dwordx4 %0, %1, off sc0 sc1\n\t"
                   "s_waitcnt vmcnt(0)"
                   : "=v"(pw) : "v"(src) : "memory");
      if ((pw[1] == tg) & (pw[3] == tg)) break;
    }
    float* sb = smem + (t & 1) * 1056;
    sb[stg + 0] = __uint_as_float(pw[0]);
    sb[stg + 1] = __uint_as_float(pw[2]);
    __syncthreads();  // the only per-step barrier (parity dbuf covers WAR)
    // 128 FMAs, all literal indices
    const float* hs = sb + u * 33;
    float a0 = 0.f, a1 = 0.f, a2 = 0.f, a3 = 0.f;
#define FMA_GRP(i) do {                                                  \
    const float h0 = hs[4*(i)+0], h1 = hs[4*(i)+1];                      \
    const float h2 = hs[4*(i)+2], h3 = hs[4*(i)+3];                      \
    a0 = fmaf(W0[i][0], h0, a0); a0 = fmaf(W0[i][1], h1, a0);            \
    a0 = fmaf(W0[i][2], h2, a0); a0 = fmaf(W0[i][3], h3, a0);            \
    a1 = fmaf(W1[i][0], h0, a1); a1 = fmaf(W1[i][1], h1, a1);            \
    a1 = fmaf(W1[i][2], h2, a1); a1 = fmaf(W1[i][3], h3, a1);            \
    a2 = fmaf(W2[i][0], h0, a2); a2 = fmaf(W2[i][1], h1, a2);            \
    a2 = fmaf(W2[i][2], h2, a2); a2 = fmaf(W2[i][3], h3, a2);            \
    a3 = fmaf(W3[i][0], h0, a3); a3 = fmaf(W3[i][1], h1, a3);            \
    a3 = fmaf(W3[i][2], h2, a3); a3 = fmaf(W3[i][3], h3, a3); } while (0)
    FMA_GRP(0); FMA_GRP(1); FMA_GRP(2); FMA_GRP(3);
    FMA_GRP(4); FMA_GRP(5); FMA_GRP(6); FMA_GRP(7);
#undef FMA_GRP
    // 32-lane butterfly reduce (lanes u and u+32 hold identical values)
#pragma unroll
    for (int offx = 16; offx >= 1; offx >>= 1) {
      a0 += __shfl_xor(a0, offx, 32);
      a1 += __shfl_xor(a1, offx, 32);
      a2 += __shfl_xor(a2, offx, 32);
      a3 += __shfl_xor(a3, offx, 32);
    }
    if (u == 0) {
      const float gi = a0 + gxc0;
      const float gf = a1 + gxc1;
      const float gg = a2 + gxc2;
      const float go = a3 + gxc3;
      c = sigmoid_f(gf) * c + sigmoid_f(gi) * tanh_f(gg);
      const float hn = sigmoid_f(go) * tanh_f(c);
      const u64 pk = ((u64)(unsigned)(t + 1) << 32) | (u64)__float_as_uint(hn);
      // publish via atomic EXCHANGE: executes at the LLC (coherence point).
      (void)__hip_atomic_exchange(hb + (((t + 1) & 1) << 10) + j, pk,
                                  __ATOMIC_RELAXED, AGENT);
      gxc0 = gxn0; gxc1 = gxn1; gxc2 = gxn2; gxc3 = gxn3;
    }
  }
}

// ---------------------------------------------------------------------------
// head: feat = [v1, v2, |v1-v2|, v1*v2]; out = fc2_w @ (fc1_w@feat + fc1_b) + fc2_b
// ---------------------------------------------------------------------------
__global__ __launch_bounds__(512) void head_kernel(
    const u64* __restrict__ h1p, const u64* __restrict__ h2p,
    const float* __restrict__ fc1_w, const float* __restrict__ fc1_b,
    const float* __restrict__ fc2_w, const float* __restrict__ fc2_b,
    float* __restrict__ out) {
  __shared__ float feat[4 * H_DIM];
  __shared__ float yv[512];
  const int tid = threadIdx.x;
  for (int i = tid; i < H_DIM; i += 512) {
    const float a = __uint_as_float((unsigned)h1p[i]);
    const float bsv = __uint_as_float((unsigned)h2p[i]);
    feat[i] = a;
    feat[H_DIM + i] = bsv;
    feat[2 * H_DIM + i] = fabsf(a - bsv);
    feat[3 * H_DIM + i] = a * bsv;
  }
  __syncthreads();
  float s = fc1_b[tid];
  const float4* wr = (const float4*)(fc1_w + (size_t)tid * (4 * H_DIM));
#pragma unroll 4
  for (int k4 = 0; k4 < H_DIM; ++k4) {
    const float4 wv = wr[k4];
    const float4 fv = *(const float4*)&feat[k4 * 4];
    s = fmaf(wv.x, fv.x, s);
    s = fmaf(wv.y, fv.y, s);
    s = fmaf(wv.z, fv.z, s);
    s = fmaf(wv.w, fv.w, s);
  }
  yv[tid] = s;
  __syncthreads();
  if (tid < 64) {
    float s0 = 0.f, s1 = 0.f;
    for (int i = tid; i < 512; i += 64) {
      s0 = fmaf(fc2_w[i], yv[i], s0);
      s1 = fmaf(fc2_w[512 + i], yv[i], s1);
    }
#pragma unroll
    for (int off = 32; off >= 1; off >>= 1) {
      s0 += __shfl_down(s0, off);
      s1 += __shfl_down(s1, off);
    }
    if (tid == 0) {
      out[0] = s0 + fc2_b[0];
      out[1] = s1 + fc2_b[1];
    }
  }
}

// ---------------------------------------------------------------------------
extern "C" void kernel_launch(void* const* d_in, const int* in_sizes, int n_in,
                              void* d_out, int out_size, void* d_ws, size_t ws_size,
                              hipStream_t stream) {
  const int*   s1    = (const int*)  d_in[0];
  const int*   s2    = (const int*)  d_in[1];
  const float* emb   = (const float*)d_in[2];
  const float* W_ih  = (const float*)d_in[3];
  const float* W_hh  = (const float*)d_in[4];
  const float* b_ih  = (const float*)d_in[5];
  const float* b_hh  = (const float*)d_in[6];
  const float* h01   = (const float*)d_in[7];
  const float* c01   = (const float*)d_in[8];
  const float* h02   = (const float*)d_in[9];
  const float* c02   = (const float*)d_in[10];
  const float* fc1_w = (const float*)d_in[11];
  const float* fc1_b = (const float*)d_in[12];
  const float* fc2_w = (const float*)d_in[13];
  const float* fc2_b = (const float*)d_in[14];
  float* out = (float*)d_out;

  // workspace layout
  const size_t GX = (size_t)L_SEQ * 4 * H_DIM;  // 8M floats per sequence
  float* ws = (float*)d_ws;
  float* gx1 = ws;
  float* gx2 = ws + GX;
  u64* hb1 = (u64*)(ws + 2 * GX);      // [2][1024] packed (tag|h) double buffer
  u64* hb2 = hb1 + 2 * H_DIM;
  int* done = (int*)(hb2 + 2 * H_DIM); // 32 tile-ready counters

  init_kernel<<<1, 256, 0, stream>>>(h01, h02, hb1, hb2, done);

  void* args[] = { (void*)&W_hh, (void*)&s1, (void*)&s2, (void*)&emb,
                   (void*)&W_ih, (void*)&b_ih, (void*)&b_hh,
                   (void*)&gx1, (void*)&gx2, (void*)&c01, (void*)&c02,
                   (void*)&hb1, (void*)&hb2, (void*)&done };
  hipLaunchCooperativeKernel(reinterpret_cast<void*>(fused_kernel),
                             dim3(2 * NBLK + NWORK), dim3(SCAN_T), args, 0, stream);

  head_kernel<<<1, 512, 0, stream>>>(hb1, hb2, fc1_w, fc1_b, fc2_w, fc2_b, out);
}